// Round 1
// 167.715 us; speedup vs baseline: 1.1247x; 1.1247x over previous
//
#include <hip/hip_runtime.h>

// Problem constants
#define S_DIM 8192
#define K_DIM 1024
#define RO_DIM 4096
#define O_DIM 64
#define SO (S_DIM * O_DIM)
#define NSLICE 16  // N/256 partial slices (was 32 with 128-tiles)

typedef __attribute__((ext_vector_type(8))) __bf16 bf16x8;
typedef __attribute__((ext_vector_type(4))) float floatx4;
typedef __attribute__((ext_vector_type(4))) unsigned short ushx4;
typedef __attribute__((ext_vector_type(8))) unsigned short ushx8;

__device__ inline unsigned short f2bf(float f) {
  unsigned u = __builtin_bit_cast(unsigned, f);
  u += 0x7fff + ((u >> 16) & 1);  // round-to-nearest-even
  return (unsigned short)(u >> 16);
}
__device__ inline float bf2f(unsigned short h) {
  unsigned u = ((unsigned)h) << 16;
  return __builtin_bit_cast(float, u);
}

// ---------------------------------------------------------------- cast X,W -> bf16
__global__ __launch_bounds__(256) void cast_kernel(const float* __restrict__ X,
                                                   const float* __restrict__ W,
                                                   unsigned short* __restrict__ Xb,
                                                   unsigned short* __restrict__ Wb) {
  const int NX4 = (S_DIM * K_DIM) / 4;
#pragma unroll
  for (int i = 0; i < 4; ++i) {
    int g = blockIdx.x * 1024 + i * 256 + threadIdx.x;
    float4 v;
    unsigned short* dst;
    if (g < NX4) {
      v = ((const float4*)X)[g];
      dst = Xb + (size_t)g * 4;
    } else {
      int j = g - NX4;
      v = ((const float4*)W)[j];
      dst = Wb + (size_t)j * 4;
    }
    ushx4 o;
    o.x = f2bf(v.x); o.y = f2bf(v.y); o.z = f2bf(v.z); o.w = f2bf(v.w);
    *(ushx4*)dst = o;
  }
}

// ---------------------------------------------------------------- 256x256 8-phase GEMM
// 8 waves (2M x 4N), per-wave 128x64 output = ONE rule's 64 columns.
// LDS: 2 x 64KB tile buffers (A half0/half1, B half0/half1 @ 16KB each) + 4KB lamsh.
// Per tile kt (4 phases): ph p reads A-frags mi={2p,2p+1} (B-frags all read at ph0,
// held in regs); stages: ph0/ph1 -> A(kt+1), ph2/ph3 -> B(kt+2); vmcnt(4) at ph3 only.
// Safety proof (in-order vmcnt retirement): at ph3's vmcnt(4) the 4 newest VMEM ops
// are always ph2+ph3's stages, so A(kt+1) [ph0/ph1] and all older loads have landed
// before the next tile's ph0 reads. WAR on LDS slots: stage issue is always >=1
// barrier after the slot's last ds_read completed (reads retire at each phase's
// lgkmcnt(0) before its pre-MFMA barrier). Tail: kt=14 -> vmcnt(0); kt=15 no stages.
// Swizzle: k-chunk ^= (row&7) (involution; pre-swizzled GLOBAL source, linear LDS
// dest for global_load_lds, swizzled ds_read addr) -> conflict-free ds_read_b128.

template <int MB>
__device__ __forceinline__ void rdA(bf16x8 (&af)[2][2], const unsigned short* As,
                                    int cA0, int cA1) {
  af[0][0] = *(const bf16x8*)(As + MB * 1024 + cA0);
  af[0][1] = *(const bf16x8*)(As + MB * 1024 + cA1);
  af[1][0] = *(const bf16x8*)(As + (MB + 1) * 1024 + cA0);
  af[1][1] = *(const bf16x8*)(As + (MB + 1) * 1024 + cA1);
}

template <int MB>
__device__ __forceinline__ void mfma8(floatx4 (&acc)[8][4], const bf16x8 (&af)[2][2],
                                      const bf16x8 (&bfr)[4][2]) {
  __builtin_amdgcn_s_setprio(1);
#pragma unroll
  for (int ii = 0; ii < 2; ++ii)
#pragma unroll
    for (int ni = 0; ni < 4; ++ni) {
      acc[MB + ii][ni] = __builtin_amdgcn_mfma_f32_16x16x32_bf16(
          af[ii][0], bfr[ni][0], acc[MB + ii][ni], 0, 0, 0);
      acc[MB + ii][ni] = __builtin_amdgcn_mfma_f32_16x16x32_bf16(
          af[ii][1], bfr[ni][1], acc[MB + ii][ni], 0, 0, 0);
    }
  __builtin_amdgcn_s_setprio(0);
}

#define BAR() __builtin_amdgcn_s_barrier()
#define LGKM0() asm volatile("s_waitcnt lgkmcnt(0)" ::: "memory")

__global__ __launch_bounds__(512, 2) void gemm_kernel(const unsigned short* __restrict__ Xb,
                                                      const unsigned short* __restrict__ Wb,
                                                      const float* __restrict__ bias,
                                                      const float* __restrict__ lam,
                                                      unsigned short* __restrict__ partial) {
  __shared__ __align__(16) unsigned char smem[135168];  // 128KB buffers + 4KB lamsh
  unsigned short* sm = (unsigned short*)smem;
  float* lamsh = (float*)(smem + 131072);  // [256][4]

  const int t = threadIdx.x;
  const int lane = t & 63;
  const int w = t >> 6;
  const int wm = w >> 2;   // M half: rows wm*128..+127
  const int wn = w & 3;    // N quarter = rule index within block
  const int quad = lane >> 4;
  const int l16 = lane & 15;

  // XCD-aware swizzle (512 blocks, 512%8==0 -> simple form is bijective)
  int id = blockIdx.y * 16 + blockIdx.x;
  int swz = (id & 7) * 64 + (id >> 3);
  const int bx = swz & 15;
  const int by = swz >> 4;
  const int gm0 = by * 256;
  const int gn0 = bx * 256;

  // staging per-thread constants (gcc = chunk ^ (row&7) is thread-invariant)
  const int rowt = t >> 3;                       // 0..63
  const int gcc = (t & 7) ^ (rowt & 7);
  const size_t goff = (size_t)rowt * K_DIM + (size_t)gcc * 8;
  const unsigned short* Abase = Xb + (size_t)gm0 * K_DIM;
  const unsigned short* Bbase = Wb + (size_t)gn0 * K_DIM;

  auto STAGE = [&](const unsigned short* gbase, int half, int ktile, int slotOff) {
#pragma unroll
    for (int j = 0; j < 2; ++j) {
      const unsigned short* src =
          gbase + (size_t)(half * 128 + j * 64) * K_DIM + ktile * 64 + goff;
      __builtin_amdgcn_global_load_lds(
          (const __attribute__((address_space(1))) void*)src,
          (__attribute__((address_space(3))) void*)(sm + slotOff + j * 4096 + t * 8),
          16, 0, 0);
    }
  };

  // prologue: tile0 (A0,A1,B0,B1 -> buf0) + tile1 B halves (-> buf1): 12 loads.
  // vmcnt(4): tile0's 8 loads always have >=4 younger ops following -> landed.
  STAGE(Abase, 0, 0, 0);
  STAGE(Abase, 1, 0, 8192);
  STAGE(Bbase, 0, 0, 16384);
  STAGE(Bbase, 1, 0, 24576);
  STAGE(Bbase, 0, 1, 32768 + 16384);
  STAGE(Bbase, 1, 1, 32768 + 24576);

  // lambda stage AFTER stage issue (keeps its global loads out of the oldest-8 window)
  {
    int i = t;
    lamsh[i] = lam[(size_t)(gm0 + (i >> 2)) * 64 + bx * 4 + (i & 3)];
    i = t + 512;
    lamsh[i] = lam[(size_t)(gm0 + (i >> 2)) * 64 + bx * 4 + (i & 3)];
  }
  asm volatile("s_waitcnt vmcnt(4)" ::: "memory");
  BAR();

  // acc init = bias (exact fold); placed after barrier so the 4 bias loads are
  // pinned before tile0 ph0's MFMA (they only ever add OLDER in-flight ops).
  floatx4 acc[8][4];
#pragma unroll
  for (int ni = 0; ni < 4; ++ni) {
    float bv = bias[gn0 + wn * 64 + ni * 16 + l16];
#pragma unroll
    for (int mi = 0; mi < 8; ++mi) acc[mi][ni] = (floatx4){bv, bv, bv, bv};
  }

  const int cA0 = ((quad) ^ (l16 & 7)) * 8;        // k-chunk ks=0, swizzled
  const int cA1 = ((4 + quad) ^ (l16 & 7)) * 8;    // k-chunk ks=1, swizzled

  for (int kt = 0; kt < 16; ++kt) {
    const int b = kt & 1;
    const unsigned short* As = sm + b * 32768 + wm * 8192 + l16 * 64;
    const unsigned short* Bs =
        sm + b * 32768 + 16384 + (wn >> 1) * 8192 + ((wn & 1) * 64 + l16) * 64;
    const int bufA = ((kt + 1) & 1) * 32768;  // A stages target tile kt+1's buffer
    const int bufB = b * 32768;               // B stages target tile kt+2's buffer (==b)

    bf16x8 bfr[4][2], af[2][2];

    // ---- phase 0: B frags (whole tile) + A mi 0,1; stage A(kt+1) half0
#pragma unroll
    for (int ni = 0; ni < 4; ++ni) {
      bfr[ni][0] = *(const bf16x8*)(Bs + ni * 1024 + cA0);
      bfr[ni][1] = *(const bf16x8*)(Bs + ni * 1024 + cA1);
    }
    rdA<0>(af, As, cA0, cA1);
    if (kt < 15) STAGE(Abase, 0, kt + 1, bufA + 0);
    BAR();
    LGKM0();
    mfma8<0>(acc, af, bfr);
    BAR();

    // ---- phase 1: A mi 2,3; stage A(kt+1) half1
    rdA<2>(af, As, cA0, cA1);
    if (kt < 15) STAGE(Abase, 1, kt + 1, bufA + 8192);
    BAR();
    LGKM0();
    mfma8<2>(acc, af, bfr);
    BAR();

    // ---- phase 2: A mi 4,5; stage B(kt+2) half0 (own B slots free since ph0)
    rdA<4>(af, As, cA0, cA1);
    if (kt < 14) STAGE(Bbase, 0, kt + 2, bufB + 16384);
    BAR();
    LGKM0();
    mfma8<4>(acc, af, bfr);
    BAR();

    // ---- phase 3: A mi 6,7; stage B(kt+2) half1; counted vmcnt (never 0 mid-loop)
    rdA<6>(af, As, cA0, cA1);
    if (kt < 14) {
      STAGE(Bbase, 1, kt + 2, bufB + 24576);
      asm volatile("s_waitcnt vmcnt(4)" ::: "memory");
    } else if (kt == 14) {
      asm volatile("s_waitcnt vmcnt(0)" ::: "memory");  // tail: A(15) must land
    }
    BAR();
    LGKM0();
    mfma8<6>(acc, af, bfr);
    BAR();
  }

  // ---- epilogue: rule-weighted sigmoid -> LDS region per wn (reuse buffer space),
  // then 4-rule in-block reduce -> bf16 partial slice bx. __syncthreads drains
  // lgkm so no wave overwrites a buffer another wave is still reading.
  __syncthreads();
  {
    unsigned short* yreg = sm + wn * 16384;  // [256][64], col-chunk ^= quad (banks)
#pragma unroll
    for (int mi = 0; mi < 8; ++mi) {
#pragma unroll
      for (int r = 0; r < 4; ++r) {
        int row = wm * 128 + mi * 16 + quad * 4 + r;
        float lamv = lamsh[row * 4 + wn];  // broadcast within each quad: free
#pragma unroll
        for (int ni = 0; ni < 4; ++ni) {
          float sg = 1.f / (1.f + __expf(-acc[mi][ni][r]));
          yreg[row * 64 + ((ni ^ quad) * 16) + l16] = f2bf(lamv * sg);
        }
      }
    }
  }
  __syncthreads();
  {
    unsigned short* pb = partial + (size_t)bx * SO + (size_t)gm0 * 64;
#pragma unroll
    for (int g = 0; g < 4; ++g) {
      int idx = g * 4096 + t * 8;  // lane-contiguous global writes
      int row = idx >> 6;
      int c = idx & 63;
      int phys = row * 64 + ((((c >> 4) ^ ((row >> 2) & 3))) << 4) + (c & 15);
      float s[8];
#pragma unroll
      for (int j = 0; j < 8; ++j) s[j] = 0.f;
#pragma unroll
      for (int q = 0; q < 4; ++q) {
        ushx8 v = *(const ushx8*)(sm + q * 16384 + phys);
#pragma unroll
        for (int j = 0; j < 8; ++j) s[j] += bf2f(v[j]);
      }
      ushx8 o;
#pragma unroll
      for (int j = 0; j < 8; ++j) o[j] = f2bf(s[j]);
      *(ushx8*)(pb + idx) = o;
    }
  }
}

// ---------------------------------------------------------------- final reduce over 16 N-tiles
__global__ __launch_bounds__(256) void reduce_kernel(const unsigned short* __restrict__ partial,
                                                     float* __restrict__ Y) {
  int i4 = blockIdx.x * 256 + threadIdx.x;
  float s0 = 0.f, s1 = 0.f, s2 = 0.f, s3 = 0.f;
#pragma unroll
  for (int c = 0; c < NSLICE; ++c) {
    ushx4 v = ((const ushx4*)(partial + (size_t)c * SO))[i4];
    s0 += bf2f(v.x); s1 += bf2f(v.y); s2 += bf2f(v.z); s3 += bf2f(v.w);
  }
  ((float4*)Y)[i4] = (float4){s0, s1, s2, s3};
}

extern "C" void kernel_launch(void* const* d_in, const int* in_sizes, int n_in,
                              void* d_out, int out_size, void* d_ws, size_t ws_size,
                              hipStream_t stream) {
  const float* X = (const float*)d_in[0];     // [8192,1024]
  const float* W = (const float*)d_in[1];     // [4096,1024]
  const float* b = (const float*)d_in[2];     // [4096]
  const float* lam = (const float*)d_in[3];   // [8192,64]
  float* Y = (float*)d_out;                   // [8192,64]

  unsigned short* Xb = (unsigned short*)d_ws;                 // 16 MB
  unsigned short* Wb = Xb + (size_t)S_DIM * K_DIM;            // 8 MB
  unsigned short* partial = Wb + (size_t)RO_DIM * K_DIM;      // 16 slices x 1 MB

  int nCast = ((S_DIM + RO_DIM) * K_DIM / 4) / 1024;  // 3072 blocks
  cast_kernel<<<nCast, 256, 0, stream>>>(X, W, Xb, Wb);

  dim3 g(RO_DIM / 256, S_DIM / 256);  // (16, 32) = 512 blocks, 512 threads
  gemm_kernel<<<g, 512, 0, stream>>>(Xb, Wb, b, lam, partial);

  reduce_kernel<<<SO / 1024, 256, 0, stream>>>(partial, Y);
}